// Round 7
// baseline (360.445 us; speedup 1.0000x reference)
//
#include <hip/hip_runtime.h>

typedef short  short8  __attribute__((ext_vector_type(8)));
typedef float  floatx4 __attribute__((ext_vector_type(4)));

#define TT 512
#define DD 32
#define HH 128
#define AA 10
#define LOG2E 1.44269504088896340736f

__device__ __forceinline__ unsigned f2bf(float f) {
    unsigned u = __builtin_bit_cast(unsigned, f);
    return (u + 0x7fffu + ((u >> 16) & 1u)) >> 16;   // RNE f32 -> bf16
}

__device__ __forceinline__ short8 cvt8(floatx4 a, floatx4 b) {
    short8 r;
    r[0] = (short)f2bf(a[0]); r[1] = (short)f2bf(a[1]);
    r[2] = (short)f2bf(a[2]); r[3] = (short)f2bf(a[3]);
    r[4] = (short)f2bf(b[0]); r[5] = (short)f2bf(b[1]);
    r[6] = (short)f2bf(b[2]); r[7] = (short)f2bf(b[3]);
    return r;
}

// activations on pre-scaled gates (scale folded into weights/bias)
__device__ __forceinline__ float sig2(float a) {   // a = -x*log2e
    return __builtin_amdgcn_rcpf(1.0f + __builtin_amdgcn_exp2f(a));
}
__device__ __forceinline__ float tanh2(float a) {  // a = 2x*log2e
    return 1.0f - 2.0f * __builtin_amdgcn_rcpf(1.0f + __builtin_amdgcn_exp2f(a));
}

// lgkm-only step barrier: x prefetch loads float across it
__device__ __forceinline__ void step_barrier() {
    asm volatile("s_waitcnt lgkmcnt(0)" ::: "memory");
    __builtin_amdgcn_s_barrier();
    asm volatile("" ::: "memory");
}

// Prepass: x (f32) -> bf16 in d_ws, same [B][T][D] layout.
__global__ __launch_bounds__(256)
void xcvt(const float* __restrict__ x, unsigned short* __restrict__ xb) {
    const long i = (long)blockIdx.x * 256 + threadIdx.x;
    floatx4 a = *(const floatx4*)(x + 8 * i);
    floatx4 b = *(const floatx4*)(x + 8 * i + 4);
    *(short8*)(xb + 8 * i) = cvt8(a, b);
}

// One block = 4 batch rows, 4 waves (256 thr); 256 blocks = 1 per CU.
// Wave w owns ALL FOUR gates for j in [32w, 32w+32) = 8 tiles, 40 MFMA.
// B-operand (h) is shared across a wave's tiles -> still only 4 ds_read_b128
// per wave per step: halves the per-CU LDS burst AND barrier arrivals vs the
// 8-wave layout, with conserved MFMA/VALU issue work and doubled MFMA ILP.
// Each lane packs TWO (b,j) quads (jb=0,1 -> j=jp0, jp0+16).
// h layout: addr(b,j) = b*256 + ((2j+32b)&255)  (rotation swizzle, ~0 conflicts)
template<int USEWS>
__global__ __launch_bounds__(256, 1)
void lstm_fused(const float* __restrict__ x,    const unsigned short* __restrict__ xbf,
                const float* __restrict__ W_ih, const float* __restrict__ W_hh,
                const float* __restrict__ b_ih, const float* __restrict__ b_hh,
                const float* __restrict__ fc_w, const float* __restrict__ fc_b,
                float* __restrict__ out)
{
    __shared__ unsigned short h_lds[2][4 * HH];    // 2 KiB, dbuf
    __shared__ float hq[4][HH + 4];

    const int tid  = threadIdx.x;
    const int lane = tid & 63;
    const int w    = tid >> 6;      // wave 0..3
    const int l15  = lane & 15;
    const int lgrp = lane >> 4;     // k-group 0..3
    const int bloc = l15 & 3;       // batch row of this lane's B-frag

    const long bglob = (long)blockIdx.x * 4 + bloc;

    // ---- resident A-fragments (bf16, gate-scaled) + bias C-operands ----
    // tile (tg, jb): rows ga = 128*tg + 16*(2w+jb) + l15
    short8  afr[4][2][5];
    floatx4 biasv[4][2];
    #pragma unroll
    for (int tg = 0; tg < 4; ++tg) {
        const float sc = (tg == 2) ? (2.0f * LOG2E) : (-LOG2E);
        #pragma unroll
        for (int jb = 0; jb < 2; ++jb) {
            const int ga = 128 * tg + 16 * (2 * w + jb) + l15;
            #pragma unroll
            for (int s = 0; s < 4; ++s) {
                const float* p = W_hh + ga * HH + 32 * s + 8 * lgrp;
                afr[tg][jb][s] = cvt8(*(const floatx4*)p * sc, *(const floatx4*)(p + 4) * sc);
            }
            {
                const float* p = W_ih + ga * DD + 8 * lgrp;
                afr[tg][jb][4] = cvt8(*(const floatx4*)p * sc, *(const floatx4*)(p + 4) * sc);
            }
            #pragma unroll
            for (int r = 0; r < 4; ++r) {
                const int gd = 128 * tg + 16 * (2 * w + jb) + 4 * lgrp + r;
                biasv[tg][jb][r] = (b_ih[gd] + b_hh[gd]) * sc;
            }
        }
    }

    // zero both h buffers: 512 dwords, 256 threads
    ((unsigned*)h_lds)[tid]       = 0u;
    ((unsigned*)h_lds)[tid + 256] = 0u;
    __syncthreads();

    // packed-lane mapping: quad element rs = l15>>2; two j's per lane
    const int rs  = l15 >> 2;
    const bool sb0 = (rs & 1) != 0;
    const bool sb1 = (rs & 2) != 0;
    const int bp  = bloc;
    const int jp0 = 32 * w + 4 * lgrp + rs;
    const int jp1 = jp0 + 16;

    // hoisted LDS offsets (rotation swizzle)
    const int rb = bloc * 256;
    const int rdA0 = rb + ((16 * lgrp + 32 * bloc) & 255);
    const int rdA1 = rb + ((64 + 16 * lgrp + 32 * bloc) & 255);
    const int rdA2 = rb + ((128 + 16 * lgrp + 32 * bloc) & 255);
    const int rdA3 = rb + ((192 + 16 * lgrp + 32 * bloc) & 255);
    const int rdB0 = rdA0 + 1024, rdB1 = rdA1 + 1024, rdB2 = rdA2 + 1024, rdB3 = rdA3 + 1024;
    const int wrA0 = bp * 256 + ((2 * jp0 + 32 * bp) & 255);
    const int wrA1 = bp * 256 + ((2 * jp1 + 32 * bp) & 255);
    const int wrB0 = wrA0 + 1024, wrB1 = wrA1 + 1024;

    // x for t=0
    short8  xf;
    floatx4 xa, xb_;
    if constexpr (USEWS) {
        xf = *(const short8*)(xbf + (bglob * TT) * DD + 8 * lgrp);
    } else {
        xa  = *(const floatx4*)(x + (bglob * TT) * DD + 8 * lgrp);
        xb_ = *(const floatx4*)(x + (bglob * TT) * DD + 8 * lgrp + 4);
    }

    float cv0 = 0.f, cv1 = 0.f, hv0 = 0.f, hv1 = 0.f;
    const char* lbase = (const char*)h_lds;

    auto STEP = [&](int r0, int r1, int r2, int r3, int wo0, int wo1, int t) {
        short8 xcur;
        const int tn = (t + 1 < TT) ? (t + 1) : (TT - 1);   // uniform
        if constexpr (USEWS) {
            xcur = xf;
            xf = *(const short8*)(xbf + (bglob * TT + tn) * DD + 8 * lgrp);
        } else {
            xcur = cvt8(xa, xb_);
            const float* xp = x + (bglob * TT + tn) * DD + 8 * lgrp;
            xa  = *(const floatx4*)(xp);
            xb_ = *(const floatx4*)(xp + 4);
        }

        short8 hb0 = *(const short8*)(lbase + r0);
        short8 hb1 = *(const short8*)(lbase + r1);
        short8 hb2 = *(const short8*)(lbase + r2);
        short8 hb3 = *(const short8*)(lbase + r3);

        // 8 independent depth-5 MFMA chains (B-frags shared across tiles)
        floatx4 acc[4][2];
        #pragma unroll
        for (int tg = 0; tg < 4; ++tg)
            #pragma unroll
            for (int jb = 0; jb < 2; ++jb)
                acc[tg][jb] = __builtin_amdgcn_mfma_f32_16x16x32_bf16(afr[tg][jb][4], xcur, biasv[tg][jb], 0, 0, 0);
        #pragma unroll
        for (int tg = 0; tg < 4; ++tg)
            #pragma unroll
            for (int jb = 0; jb < 2; ++jb)
                acc[tg][jb] = __builtin_amdgcn_mfma_f32_16x16x32_bf16(afr[tg][jb][0], hb0, acc[tg][jb], 0, 0, 0);
        #pragma unroll
        for (int tg = 0; tg < 4; ++tg)
            #pragma unroll
            for (int jb = 0; jb < 2; ++jb)
                acc[tg][jb] = __builtin_amdgcn_mfma_f32_16x16x32_bf16(afr[tg][jb][1], hb1, acc[tg][jb], 0, 0, 0);
        #pragma unroll
        for (int tg = 0; tg < 4; ++tg)
            #pragma unroll
            for (int jb = 0; jb < 2; ++jb)
                acc[tg][jb] = __builtin_amdgcn_mfma_f32_16x16x32_bf16(afr[tg][jb][2], hb2, acc[tg][jb], 0, 0, 0);
        #pragma unroll
        for (int tg = 0; tg < 4; ++tg)
            #pragma unroll
            for (int jb = 0; jb < 2; ++jb)
                acc[tg][jb] = __builtin_amdgcn_mfma_f32_16x16x32_bf16(afr[tg][jb][3], hb3, acc[tg][jb], 0, 0, 0);

        // pack via register select (rs = l15>>2), both jb's for ILP
        float g0[4], g1[4];
        #pragma unroll
        for (int tg = 0; tg < 4; ++tg) {
            const float a01 = sb0 ? acc[tg][0][1] : acc[tg][0][0];
            const float a23 = sb0 ? acc[tg][0][3] : acc[tg][0][2];
            g0[tg] = sb1 ? a23 : a01;
            const float b01 = sb0 ? acc[tg][1][1] : acc[tg][1][0];
            const float b23 = sb0 ? acc[tg][1][3] : acc[tg][1][2];
            g1[tg] = sb1 ? b23 : b01;
        }

        const float iv0 = sig2(g0[0]), iv1 = sig2(g1[0]);
        const float fv0 = sig2(g0[1]), fv1 = sig2(g1[1]);
        const float gv0 = tanh2(g0[2]), gv1 = tanh2(g1[2]);
        const float ov0 = sig2(g0[3]), ov1 = sig2(g1[3]);
        cv0 = fv0 * cv0 + iv0 * gv0;
        cv1 = fv1 * cv1 + iv1 * gv1;
        hv0 = ov0 * tanh2(cv0 * (2.0f * LOG2E));
        hv1 = ov1 * tanh2(cv1 * (2.0f * LOG2E));

        // pack both h's with one v_cvt_pk_bf16_f32, write b16 lo/hi
        unsigned hp;
        asm("v_cvt_pk_bf16_f32 %0, %1, %2" : "=v"(hp) : "v"(hv0), "v"(hv1));
        *(unsigned short*)((char*)h_lds + wo0) = (unsigned short)hp;
        *(unsigned short*)((char*)h_lds + wo1) = (unsigned short)(hp >> 16);
        step_barrier();
    };

    #pragma unroll 1
    for (int t = 0; t < TT; t += 2) {
        STEP(rdA0, rdA1, rdA2, rdA3, wrB0, wrB1, t);       // read buf0, write buf1
        STEP(rdB0, rdB1, rdB2, rdB3, wrA0, wrA1, t + 1);   // read buf1, write buf0
    }

    // ---- epilogue: h_n, c_n, q = h @ fc_w^T + fc_b ----
    {
        const long bg = (long)blockIdx.x * 4 + bp;
        out[10240 + bg * HH + jp0]          = hv0;   // h_n
        out[10240 + bg * HH + jp1]          = hv1;
        out[10240 + 131072 + bg * HH + jp0] = cv0;   // c_n
        out[10240 + 131072 + bg * HH + jp1] = cv1;
        hq[bp][jp0] = hv0;
        hq[bp][jp1] = hv1;
    }
    __syncthreads();
    if (tid < 4 * AA) {
        const int b = tid / AA, a = tid - AA * b;
        float s = fc_b[a];
        const float* fw = fc_w + a * HH;
        const float* hr = &hq[b][0];
        #pragma unroll 8
        for (int j = 0; j < HH; ++j) s = fmaf(hr[j], fw[j], s);
        out[((long)blockIdx.x * 4 + b) * AA + a] = s;
    }
}

extern "C" void kernel_launch(void* const* d_in, const int* in_sizes, int n_in,
                              void* d_out, int out_size, void* d_ws, size_t ws_size,
                              hipStream_t stream) {
    const float* x    = (const float*)d_in[0];
    const float* W_ih = (const float*)d_in[1];
    const float* W_hh = (const float*)d_in[2];
    const float* b_ih = (const float*)d_in[3];
    const float* b_hh = (const float*)d_in[4];
    const float* fc_w = (const float*)d_in[5];
    const float* fc_b = (const float*)d_in[6];
    float* out = (float*)d_out;

    const size_t xelems = (size_t)1024 * TT * DD;       // 16.78M
    if (ws_size >= xelems * sizeof(unsigned short)) {
        unsigned short* xb = (unsigned short*)d_ws;
        xcvt<<<dim3(8192), dim3(256), 0, stream>>>(x, xb);
        lstm_fused<1><<<dim3(256), dim3(256), 0, stream>>>(
            x, xb, W_ih, W_hh, b_ih, b_hh, fc_w, fc_b, out);
    } else {
        lstm_fused<0><<<dim3(256), dim3(256), 0, stream>>>(
            x, nullptr, W_ih, W_hh, b_ih, b_hh, fc_w, fc_b, out);
    }
}